// Round 1
// 73.984 us; speedup vs baseline: 1.1072x; 1.1072x over previous
//
#include <hip/hip_runtime.h>

#ifndef __has_builtin
#define __has_builtin(x) 0
#endif

__device__ __forceinline__ float fexp2(float v) {
#if __has_builtin(__builtin_amdgcn_exp2f)
    return __builtin_amdgcn_exp2f(v);   // raw v_exp_f32
#else
    return exp2f(v);
#endif
}
__device__ __forceinline__ float frcp(float v) {
#if __has_builtin(__builtin_amdgcn_rcpf)
    return __builtin_amdgcn_rcpf(v);    // raw v_rcp_f32 (~1 ulp; threshold 1.5e-2)
#else
    return 1.0f / v;
#endif
}

// Problem constants: B, CIN, H, W = 8, 1, 192, 192; COUT, KH, KW = 8, 7, 7
constexpr int B_    = 8;
constexpr int H_    = 192;
constexpr int W_    = 192;
constexpr int COUT_ = 8;
constexpr int KH_   = 7;
constexpr int KW_   = 7;
constexpr int HO_   = H_ - KH_ + 1;  // 186
constexpr int WO_   = W_ - KW_ + 1;  // 186
constexpr float LOG2E = 1.44269504088896340736f;

constexpr int TX   = 64;             // output tile x per block
constexpr int TY   = 8;              // output tile y per block
constexpr int IX   = TX + KW_ - 1;   // 70 input cols staged
constexpr int IY   = TY + KH_ - 1;   // 14 input rows staged
constexpr int NPIX = IX * IY;        // 980

// ws table: per (c,ky) one 16-float row: [F0..F6, 0, G0..G6, 0]
// F = exp(a*f) (as exp2 of a*log2e*f), G = F*f. One s_load_dwordx16 per row.
__global__ void smorph_setup(const float* __restrict__ filt,
                             const float* __restrict__ alpha,
                             float* __restrict__ ws) {
    int i = threadIdx.x;                 // 64 threads, 56 active
    if (i < COUT_ * KH_) {
        int c = i / 7, ky = i - c * 7;
        float a2 = alpha[c] * LOG2E;
        float* t = ws + (c * 7 + ky) * 16;
#pragma unroll
        for (int kx = 0; kx < 7; ++kx) {
            float f = filt[(c * 7 + ky) * 7 + kx];
            float F = fexp2(a2 * f);
            t[kx]     = F;
            t[8 + kx] = F * f;
        }
        t[7] = 0.f; t[15] = 0.f;
    }
}

// exp(a(x+f)) = P * F_k with P = exp2(a2*x).  H = x*P.
// num = sum_k (F_k*H + G_k*P); den = sum_k F_k*P; out = num/den.
//
// CHANGE vs prev: channel loop split across grid.z (z = b*COUT + c).
// 576 blocks (2.25 waves/SIMD, latency-bound) -> 4608 blocks (~6-8
// resident blocks/CU). Single LDS buffer, single barrier per block.
// Total exp/FMA/LDS work unchanged; x-tile global re-read (x8) is
// L2-resident (consecutive z share the same 147 KB x plane).
__global__ __launch_bounds__(256) void smorph_main(
    const float* __restrict__ x,      // (B,1,H,W)
    const float* __restrict__ alpha,  // (COUT,1)
    const float* __restrict__ fg,     // setup table
    float* __restrict__ out)          // (B,COUT,HO,WO)
{
    __shared__ __align__(16) float2 PH[IY * IX];   // 7840 B

    const int tx  = threadIdx.x;      // 0..31
    const int ty  = threadIdx.y;      // 0..7
    const int tid = ty * 32 + tx;
    const int bx0 = blockIdx.x * TX;
    const int by0 = blockIdx.y * TY;
    const int z   = blockIdx.z;       // b*COUT + c
    const int c   = z & 7;
    const float* xb = x + (z >> 3) * (H_ * W_);
    const float a2  = alpha[c] * LOG2E;   // uniform -> s_load

    // Four static staging slots (no dynamic arrays -> stays in VGPRs).
    const int i0 = tid, i1 = tid + 256, i2 = tid + 512, i3 = tid + 768;
    const int iy0 = i0 / IX, ix0 = i0 - iy0 * IX;
    const int iy1 = i1 / IX, ix1 = i1 - iy1 * IX;
    const int iy2 = i2 / IX, ix2 = i2 - iy2 * IX;
    const int iy3 = i3 / IX, ix3 = i3 - iy3 * IX;
    const bool has3 = (i3 < NPIX);

    // Load x tile; clamped coords only feed masked outputs.
    const float xv0 = xb[min(by0 + iy0, H_ - 1) * W_ + min(bx0 + ix0, W_ - 1)];
    const float xv1 = xb[min(by0 + iy1, H_ - 1) * W_ + min(bx0 + ix1, W_ - 1)];
    const float xv2 = xb[min(by0 + iy2, H_ - 1) * W_ + min(bx0 + ix2, W_ - 1)];
    const float xv3 = has3 ? xb[min(by0 + iy3, H_ - 1) * W_ + min(bx0 + ix3, W_ - 1)] : 0.f;

    // Phase 1: P,H for this block's channel (4 exps/thread, ds_write_b64 each).
    {
        float P;
        P = fexp2(a2 * xv0); PH[iy0 * IX + ix0] = make_float2(P, xv0 * P);
        P = fexp2(a2 * xv1); PH[iy1 * IX + ix1] = make_float2(P, xv1 * P);
        P = fexp2(a2 * xv2); PH[iy2 * IX + ix2] = make_float2(P, xv2 * P);
        if (has3) { P = fexp2(a2 * xv3); PH[iy3 * IX + ix3] = make_float2(P, xv3 * P); }
    }
    __syncthreads();   // the only barrier in the kernel

    // Phase 2: 7x7 correlation, 2 outputs/thread.
    const int ox = bx0 + 2 * tx;
    const int oy = by0 + ty;
    const bool valid = (ox + 1 < WO_) && (oy < HO_);  // ox even: both-or-neither

    float num0 = 0.f, den0 = 0.f, num1 = 0.f, den1 = 0.f;
    const float* tc = fg + c * (7 * 16);
#pragma unroll
    for (int ky = 0; ky < KH_; ++ky) {
        const float* t = tc + ky * 16;   // uniform -> s_load_dwordx16
        const float4* rp = (const float4*)&PH[(ty + ky) * IX + 2 * tx];
        float4 q0 = rp[0], q1 = rp[1], q2 = rp[2], q3 = rp[3];
        float P[8]  = {q0.x, q0.z, q1.x, q1.z, q2.x, q2.z, q3.x, q3.z};
        float Hh[8] = {q0.y, q0.w, q1.y, q1.w, q2.y, q2.w, q3.y, q3.w};
#pragma unroll
        for (int kx = 0; kx < 7; ++kx) {
            const float F = t[kx], G = t[8 + kx];
            num0 = fmaf(F, Hh[kx],     num0);
            num0 = fmaf(G, P[kx],      num0);
            den0 = fmaf(F, P[kx],      den0);
            num1 = fmaf(F, Hh[kx + 1], num1);
            num1 = fmaf(G, P[kx + 1],  num1);
            den1 = fmaf(F, P[kx + 1],  den1);
        }
    }

    if (valid) {
        float2 o;
        o.x = num0 * frcp(den0);
        o.y = num1 * frcp(den1);
        *(float2*)&out[(z * HO_ + oy) * WO_ + ox] = o;
    }
}

extern "C" void kernel_launch(void* const* d_in, const int* in_sizes, int n_in,
                              void* d_out, int out_size, void* d_ws, size_t ws_size,
                              hipStream_t stream) {
    const float* x     = (const float*)d_in[0];
    const float* filt  = (const float*)d_in[1];
    const float* alpha = (const float*)d_in[2];
    float* out = (float*)d_out;
    float* ws  = (float*)d_ws;

    smorph_setup<<<1, 64, 0, stream>>>(filt, alpha, ws);

    dim3 block(32, 8, 1);
    dim3 grid((WO_ + TX - 1) / TX, (HO_ + TY - 1) / TY, B_ * COUT_);  // (3, 24, 64)
    smorph_main<<<grid, block, 0, stream>>>(x, alpha, ws, out);
}